// Round 10
// baseline (117.336 us; speedup 1.0000x reference)
//
#include <hip/hip_runtime.h>
#include <math.h>

#define FF 256
#define CC 100000
#define PMARG 0.2f
#define NMARG 0.3f

// ---- new-path ws layout ----
#define W2_A 0                    // floats: 8192 (32KB A-pack, bf16 frags)
#define W2_GRAM 8192              // 4096 floats
#define W2_SE 12288               // 64 floats
#define W2_PART 12352             // NB2*64 = 200000 floats
#define W2_VPACK_BYTES 849408ULL  // byte offset of vpack (16B aligned)
#define NB2 3125                  // gemm blocks (2 col-tiles of 16 each)
#define PREPB 1563                // vpack prep blocks (64 V rows each)
#define WS2_NEED (W2_VPACK_BYTES + 6256ULL * 8 * 64 * 16)

// ---- fallback (R9) ws layout ----
#define FB_GRAM 8192
#define FB_PART 12288
#define FB_SE 112320
#define FB_NGB 1563
#define FB_CGB 64

typedef __attribute__((ext_vector_type(8))) short short8;   // 8 bf16 = 4 VGPR
typedef __attribute__((ext_vector_type(4))) float f32x4;

__device__ __forceinline__ float wredf(float v) {
#pragma unroll
    for (int s = 1; s < 64; s <<= 1) v += __shfl_xor(v, s, 64);
    return v;
}
__device__ __forceinline__ short f2bf(float f) {
    unsigned u = __float_as_uint(f);
    unsigned r = (u + 0x7fffu + ((u >> 16) & 1u)) >> 16;
    return (short)r;
}
__device__ __forceinline__ short8 pack8(float4 a, float4 b) {
    short8 o;
    o[0] = f2bf(a.x); o[1] = f2bf(a.y); o[2] = f2bf(a.z); o[3] = f2bf(a.w);
    o[4] = f2bf(b.x); o[5] = f2bf(b.y); o[6] = f2bf(b.z); o[7] = f2bf(b.w);
    return o;
}

// A-pack: wsa[(mt*8+ks)*64+lane] = A[mt*16+(lane&15)][ks*32+(lane>>4)*8 ..+8]
__device__ __forceinline__ void do_apack(int tid, const float4* __restrict__ in4,
                                         float* __restrict__ ws) {
    short8* __restrict__ wsa = (short8*)(ws + W2_A);
#pragma unroll
    for (int i = 0; i < 8; ++i) {
        int idx = i * 256 + tid;
        int lane = idx & 63;
        int ks = (idx >> 6) & 7;
        int mt = idx >> 9;
        int row = mt * 16 + (lane & 15);
        int kq = ks * 8 + (lane >> 4) * 2;
        wsa[idx] = pack8(in4[row * 64 + kq], in4[row * 64 + kq + 1]);
    }
}

// Gram = inputs @ inputs.T (f32, accuracy-critical), via LDS-staged inputs
__device__ __forceinline__ void do_gram(int tid, const float4* __restrict__ in4,
                                        float* __restrict__ gout, float4* sBuf) {
#pragma unroll
    for (int i = 0; i < 16; ++i) sBuf[i * 256 + tid] = in4[i * 256 + tid];
    __syncthreads();
    int r0 = (tid >> 4) << 2;
    int c0 = (tid & 15) << 2;
    float gacc[4][4];
#pragma unroll
    for (int r = 0; r < 4; ++r)
#pragma unroll
        for (int c = 0; c < 4; ++c) gacc[r][c] = 0.f;
    for (int kq = 0; kq < 64; ++kq) {
        float4 a[4], b[4];
#pragma unroll
        for (int r = 0; r < 4; ++r) a[r] = sBuf[(r0 + r) * 64 + kq];
#pragma unroll
        for (int c = 0; c < 4; ++c) b[c] = sBuf[(c0 + c) * 64 + kq];
#pragma unroll
        for (int r = 0; r < 4; ++r)
#pragma unroll
            for (int c = 0; c < 4; ++c)
                gacc[r][c] += a[r].x * b[c].x + a[r].y * b[c].y +
                              a[r].z * b[c].z + a[r].w * b[c].w;
    }
#pragma unroll
    for (int r = 0; r < 4; ++r)
#pragma unroll
        for (int c = 0; c < 4; ++c)
            gout[(r0 + r) * 64 + (c0 + c)] = gacc[r][c];
}

// blocks 0..PREPB-1: pack 64 V rows into bf16 B-fragment order (vpack).
// Stage rows coalesced via global_load_lds (source XOR-swizzled), then each
// thread emits 8 fragment packets with perfectly coalesced 16B stores.
// block PREPB: A-pack. block PREPB+1: Gram.
__global__ __launch_bounds__(256) void k_prep2(const float* __restrict__ in,
                                               const float* __restrict__ V,
                                               float* __restrict__ ws) {
    __shared__ float4 sBuf[64 * 64];   // 64KB: V rows (vpack) or inputs (Gram)
    int tid = threadIdx.x;
    int b = blockIdx.x;
    const float4* __restrict__ in4 = (const float4*)in;

    if (b >= PREPB) {
        if (b == PREPB) do_apack(tid, in4, ws);
        else            do_gram(tid, in4, ws + W2_GRAM, sBuf);
        return;
    }

    int col0 = b * 64;
    int lane = tid & 63, w = tid >> 6;
    const float4* __restrict__ V4 = (const float4*)V;
#pragma unroll
    for (int i = 0; i < 16; ++i) {
        int r = i * 4 + w;                 // wave-uniform row
        int vr = col0 + r;
        if (vr >= CC) vr = CC - 1;
        const float4* src = V4 + (size_t)vr * 64 + (lane ^ (r & 7));
        char* dst = (char*)(sBuf + (size_t)r * 64);
        __builtin_amdgcn_global_load_lds(
            (const __attribute__((address_space(1))) void*)src,
            (__attribute__((address_space(3))) void*)dst, 16, 0, 0);
    }
    __syncthreads();

    short8* __restrict__ vp = (short8*)((char*)ws + W2_VPACK_BYTES);
#pragma unroll
    for (int p = 0; p < 8; ++p) {
        int idx = p * 256 + tid;
        int l = idx & 63;
        int ks = (idx >> 6) & 7;
        int ct = idx >> 9;                 // 0..3
        int row = ct * 16 + (l & 15);
        int u = ks * 8 + (l >> 4) * 2;
        float4 x = sBuf[row * 64 + (u ^ (row & 7))];
        float4 y = sBuf[row * 64 + ((u + 1) ^ (row & 7))];
        vp[((size_t)(b * 4 + ct) * 8 + ks) * 64 + l] = pack8(x, y);
    }
}

// Streaming GEMM: 4 waves/block; wave = 16 cols (1 tile) x 32 rows.
// B-frags: 8 coalesced 16B/lane loads from vpack (prefetched, no LDS).
// A-frags: pre-packed, L1-hot. No producer barrier anywhere.
__global__ __launch_bounds__(256, 4) void k_gemm2(const float* __restrict__ ws_in,
                                                  float* __restrict__ logits,
                                                  float* __restrict__ ws) {
    __shared__ float sW[64][2];
    int tid = threadIdx.x;
    int lane = tid & 63, w = tid >> 6;
    int ctl = w & 1, rh = w >> 1;          // col-tile-local, row-half
    int ct = blockIdx.x * 2 + ctl;         // 0..6249, all fully valid (6250*16==CC)
    int g = lane >> 4, c4 = lane & 15;
    int col = ct * 16 + c4;

    const short8* __restrict__ vp =
        (const short8*)((const char*)ws_in + W2_VPACK_BYTES) + (size_t)ct * 512 + lane;
    const short8* __restrict__ ap =
        (const short8*)(ws_in + W2_A) + (size_t)rh * 16 * 64 + lane;

    short8 bfr[8];
#pragma unroll
    for (int ks = 0; ks < 8; ++ks) bfr[ks] = vp[ks * 64];   // 8 in flight

    f32x4 acc0 = {0.f, 0.f, 0.f, 0.f};
    f32x4 acc1 = {0.f, 0.f, 0.f, 0.f};
#pragma unroll
    for (int ks = 0; ks < 8; ++ks) {
        short8 a0 = ap[ks * 64];
        short8 a1 = ap[(8 + ks) * 64];
        acc0 = __builtin_amdgcn_mfma_f32_16x16x32_bf16(a0, bfr[ks], acc0, 0, 0, 0);
        acc1 = __builtin_amdgcn_mfma_f32_16x16x32_bf16(a1, bfr[ks], acc1, 0, 0, 0);
    }

#pragma unroll
    for (int q = 0; q < 2; ++q) {
        f32x4 a = q ? acc1 : acc0;
#pragma unroll
        for (int r = 0; r < 4; ++r) {
            int row = rh * 32 + q * 16 + g * 4 + r;
            float lg = a[r];
            logits[(size_t)row * CC + col] = lg;
            float e = expf(lg);                    // |logit| <= ~19, safe
            e += __shfl_xor(e, 1, 64); e += __shfl_xor(e, 2, 64);
            e += __shfl_xor(e, 4, 64); e += __shfl_xor(e, 8, 64);
            if (c4 == 0) sW[row][ctl] = e;
        }
    }
    __syncthreads();
    if (tid < 64)
        ws[W2_PART + (size_t)blockIdx.x * 64 + tid] = sW[tid][0] + sW[tid][1];
}

// ---------------- fallback path (R9), used if ws too small ----------------
__global__ __launch_bounds__(256) void k_prep_fb(const float* __restrict__ in,
                                                 float* __restrict__ ws) {
    __shared__ float4 sBuf[64 * 64];
    int tid = threadIdx.x;
    const float4* __restrict__ in4 = (const float4*)in;
    if (blockIdx.x == 0) do_apack(tid, in4, ws);
    else                 do_gram(tid, in4, ws + FB_GRAM, sBuf);
}

__global__ __launch_bounds__(512, 4) void k_gemm_fb(const float* __restrict__ V,
                                                    const float* __restrict__ ws_in,
                                                    float* __restrict__ logits,
                                                    float* __restrict__ ws) {
    __shared__ float4 sB4[FB_CGB * 64];
    __shared__ float sW[64][4];
    int tid = threadIdx.x;
    int lane = tid & 63, w = tid >> 6;
    int col0 = blockIdx.x * FB_CGB;
#pragma unroll
    for (int i = 0; i < 8; ++i) {
        int r = i * 8 + w;
        int vr = col0 + r;
        if (vr >= CC) vr = CC - 1;
        const float4* src = (const float4*)V + (size_t)vr * 64 + (lane ^ (r & 7));
        char* dst = (char*)sB4 + r * 1024;
        __builtin_amdgcn_global_load_lds(
            (const __attribute__((address_space(1))) void*)src,
            (__attribute__((address_space(3))) void*)dst, 16, 0, 0);
    }
    int cg = w & 3, h = w >> 2;
    int g = lane >> 4, c4 = lane & 15;
    int col = col0 + cg * 16 + c4;
    bool cv = col < CC;
    int rb = cg * 16 + c4;
    int m = rb & 7;
    const short8* __restrict__ wsa = (const short8*)(ws_in + W2_A);
    __syncthreads();
    f32x4 acc0 = {0.f, 0.f, 0.f, 0.f};
    f32x4 acc1 = {0.f, 0.f, 0.f, 0.f};
#pragma unroll
    for (int ks = 0; ks < 8; ++ks) {
        int u0 = ks * 8 + g * 2;
        float4 b0 = sB4[rb * 64 + (u0 ^ m)];
        float4 b1 = sB4[rb * 64 + ((u0 + 1) ^ m)];
        short8 bf = pack8(b0, b1);
        short8 a0 = wsa[((h * 2 + 0) * 8 + ks) * 64 + lane];
        short8 a1 = wsa[((h * 2 + 1) * 8 + ks) * 64 + lane];
        acc0 = __builtin_amdgcn_mfma_f32_16x16x32_bf16(a0, bf, acc0, 0, 0, 0);
        acc1 = __builtin_amdgcn_mfma_f32_16x16x32_bf16(a1, bf, acc1, 0, 0, 0);
    }
#pragma unroll
    for (int q = 0; q < 2; ++q) {
        f32x4 a = q ? acc1 : acc0;
#pragma unroll
        for (int r = 0; r < 4; ++r) {
            int row = (h * 2 + q) * 16 + g * 4 + r;
            float lg = a[r];
            if (cv) logits[(size_t)row * CC + col] = lg;
            float e = cv ? expf(lg) : 0.f;
            e += __shfl_xor(e, 1, 64); e += __shfl_xor(e, 2, 64);
            e += __shfl_xor(e, 4, 64); e += __shfl_xor(e, 8, 64);
            if (c4 == 0) sW[row][cg] = e;
        }
    }
    __syncthreads();
    if (tid < 64) {
        float t = sW[tid][0] + sW[tid][1] + sW[tid][2] + sW[tid][3];
        ws[FB_PART + (size_t)blockIdx.x * 64 + tid] = t;
    }
}

// ------------------------- shared tail kernels -------------------------
// 64 blocks (one per batch row): deterministic reduce of exp partials
__global__ __launch_bounds__(256) void k_comb(const float* __restrict__ P, int n,
                                              float* __restrict__ se) {
    __shared__ float sS[256];
    int row = blockIdx.x;
    int tid = threadIdx.x;
    float s = 0.f;
    for (int b = tid; b < n; b += 256) s += P[(size_t)b * 64 + row];
    sS[tid] = s;
    __syncthreads();
    if (tid < 128) sS[tid] += sS[tid + 128];
    __syncthreads();
    if (tid < 64) {
        float v = sS[tid] + sS[tid + 64];
        v = wredf(v);
        if (tid == 0) se[row] = v;
    }
}

__device__ __forceinline__ bool mask_at(const void* p, int idx, int mode) {
    if (mode == 0) return ((const int*)p)[idx] != 0;
    if (mode == 1) return ((const float*)p)[idx] != 0.f;
    return ((const unsigned char*)p)[idx] != 0;
}

// 1 block x 256 threads: stage G + masks into LDS, wave 0 runs the tail
__global__ __launch_bounds__(256) void k_final(const int* __restrict__ targets,
                                               const void* __restrict__ pmask,
                                               const void* __restrict__ nmask,
                                               const float* __restrict__ logits,
                                               const float* __restrict__ gram,
                                               const float* __restrict__ se,
                                               float* __restrict__ out) {
    __shared__ float sG[4096];
    __shared__ char sPM[16384];
    __shared__ char sNM[16384];
    __shared__ int sMode;
    int tid = threadIdx.x;

    float myLogit = 0.f, mySe = 0.f;
    if (tid < 64) {
        int tgt = targets[tid];
        myLogit = logits[(size_t)tid * CC + tgt];
        mySe = se[tid];
    }
    {
        const float4* __restrict__ G4 = (const float4*)gram;
        float4* sG4 = (float4*)sG;
#pragma unroll
        for (int i = 0; i < 4; ++i) sG4[tid + i * 256] = G4[tid + i * 256];
    }
    if (tid < 64) {
        const unsigned int* pw = (const unsigned int*)pmask;
        int okInt = 1, okFlt = 1;
#pragma unroll
        for (int i = 0; i < 16; ++i) {
            unsigned int wv = pw[tid * 16 + i];
            okInt = okInt && (wv <= 1u);
            okFlt = okFlt && (wv == 0u || wv == 0x3f800000u);
        }
        int mode = __all(okInt) ? 0 : (__all(okFlt) ? 1 : 2);
        if (tid == 0) sMode = mode;
    }
    __syncthreads();
    int mode = sMode;
    int mq = (mode == 2) ? 256 : 1024;
    for (int i = tid; i < mq; i += 256) {
        ((float4*)sPM)[i] = ((const float4*)pmask)[i];
        ((float4*)sNM)[i] = ((const float4*)nmask)[i];
    }
    __syncthreads();
    if (tid >= 64) return;

    int lane = tid;
    float lse = logf(mySe);
    float nll = lse - myLogit;

    float rinv = rsqrtf(sG[lane * 64 + lane]);

    float minp = INFINITY, maxthd = -INFINITY;
    for (int j = 0; j < 64; ++j) {
        float rj = __shfl(rinv, j, 64);
        float sim = sG[lane * 64 + j] * rinv * rj;
        sim = fminf(1.f, fmaxf(-1.f, sim));
        if (j != lane) {
            bool pm = mask_at(sPM, lane * 64 + j, mode);
            float ps = pm ? sim : 2.0f;
            minp = fminf(minp, ps);
            maxthd = fmaxf(maxthd, pm ? sim : -2.0f);
        }
    }
    float n_thrd = minp - NMARG;
    float p_thrd = maxthd - PMARG;

    float hps = 0.f, hns = 0.f, hpc = 0.f, hnc = 0.f;
    for (int j = 0; j < 64; ++j) {
        float rj = __shfl(rinv, j, 64);
        float sim = sG[lane * 64 + j] * rinv * rj;
        sim = fminf(1.f, fmaxf(-1.f, sim));
        if (j != lane) {
            bool pm = mask_at(sPM, lane * 64 + j, mode);
            bool nm = mask_at(sNM, lane * 64 + j, mode);
            float ps = pm ? sim : 2.0f;
            float ns = nm ? sim : 2.0f;
            if (ps < p_thrd) { hps += log1pf(expf(-ps)); hpc += 1.f; }
            if (ns < n_thrd) { hns += log1pf(expf(-ns)); hnc += 1.f; }
        }
    }

    float snll = wredf(nll);
    float shps = wredf(hps);
    float shns = wredf(hns);
    float shpc = wredf(hpc);
    float shnc = wredf(hnc);
    if (lane == 0) {
        float bu = snll * (1.f / 64.f);
        float hp = shpc > 0.f ? shps / shpc : 0.f;
        float hn = shnc > 0.f ? shns / shnc : 0.f;
        out[0] = bu + hp + hn;
    }
}

extern "C" void kernel_launch(void* const* d_in, const int* in_sizes, int n_in,
                              void* d_out, int out_size, void* d_ws, size_t ws_size,
                              hipStream_t stream) {
    const float* inputs = (const float*)d_in[0];
    const int* targets  = (const int*)d_in[1];
    const void* pmask   = d_in[2];
    const void* nmask   = d_in[3];
    const float* V      = (const float*)d_in[4];
    float* out = (float*)d_out;      // out[0] = loss
    float* logits = out + 1;         // out[1..] = logits [64][100000] row-major
    float* ws = (float*)d_ws;

    if (ws_size >= WS2_NEED) {
        hipLaunchKernelGGL(k_prep2, dim3(PREPB + 2), dim3(256), 0, stream,
                           inputs, V, ws);
        hipLaunchKernelGGL(k_gemm2, dim3(NB2), dim3(256), 0, stream,
                           ws, logits, ws);
        hipLaunchKernelGGL(k_comb, dim3(64), dim3(256), 0, stream,
                           ws + W2_PART, NB2, ws + W2_SE);
        hipLaunchKernelGGL(k_final, dim3(1), dim3(256), 0, stream,
                           targets, pmask, nmask, logits, ws + W2_GRAM,
                           ws + W2_SE, out);
    } else {
        hipLaunchKernelGGL(k_prep_fb, dim3(2), dim3(256), 0, stream, inputs, ws);
        hipLaunchKernelGGL(k_gemm_fb, dim3(FB_NGB), dim3(512), 0, stream,
                           V, ws, logits, ws);
        hipLaunchKernelGGL(k_comb, dim3(64), dim3(256), 0, stream,
                           ws + FB_PART, FB_NGB, ws + FB_SE);
        hipLaunchKernelGGL(k_final, dim3(1), dim3(256), 0, stream,
                           targets, pmask, nmask, logits, ws + FB_GRAM,
                           ws + FB_SE, out);
    }
}